// Round 6
// baseline (3003.226 us; speedup 1.0000x reference)
//
#include <hip/hip_runtime.h>

// ResidualVQ on MI355X (gfx950). ROUND 6: R5 with the cvt_pkrtz type fix.
// One-pass fp16 MFMA screen, fragment-blob codebook, 4 blocks/CU.
// z: [65536,256] f32; codebooks: [4,1024,256] f32.
// Outputs (flat f32): z_q [65536*256], codes-as-float [65536*4], loss [1].
//
// Screen: E = r16 . c16 via mfma_f32_16x16x32_f16 (single pass, RTZ fp16);
// dist_s = c2[k] - 2E. Deviation vs numpy fp32 dists: sigma ~1.1e-3 =>
// FLAG_MARGIN 1.2e-2 (~8 sigma). Flagged rows (~1.5%) get full-K
// numpy-bit-exact rescan (R3/R4-proven np_dist). Codebook pre-swizzled into
// MFMA B-fragment blob order (lane-contiguous 16B) => conflict-free LDS.
// LDS 39.4KB + VGPR<=128 => 4 blocks/CU (50% occupancy) vs R4's 17%.

#define NB 65536
#define ND 256
#define NK 1024
#define NL 4
#define MROWS 128
#define NBLK (NB / MROWS)      // 512
#define NCH 16                 // chunks of 64 codes
#define FLAG_MARGIN 1.2e-2f

typedef _Float16 half8_t __attribute__((ext_vector_type(8)));
typedef __fp16 fp16x2 __attribute__((ext_vector_type(2)));  // cvt_pkrtz return type
typedef __attribute__((ext_vector_type(4))) float f32x4;

union h8u { half8_t v; fp16x2 h2[4]; uint4 u; };

// ---- numpy-bit-exact fp32 kernels (R3-proven) ----
__device__ float np_sum256_sq(const float* __restrict__ a) {
#pragma clang fp contract(off)
  float out[2];
  for (int h = 0; h < 2; ++h) {
    const float* p = a + 128 * h;
    float r[8];
    for (int j = 0; j < 8; ++j) r[j] = p[j] * p[j];
    for (int i = 8; i < 128; i += 8)
      for (int j = 0; j < 8; ++j) r[j] += p[i + j] * p[i + j];
    out[h] = ((r[0] + r[1]) + (r[2] + r[3])) + ((r[4] + r[5]) + (r[6] + r[7]));
  }
  return out[0] + out[1];
}
__device__ float np_einsum256(const float* __restrict__ r,
                              const float* __restrict__ c) {
#pragma clang fp contract(off)
  float e[4] = {0.f, 0.f, 0.f, 0.f};
  for (int d = 0; d < 256; d += 4) {
    e[0] += r[d + 0] * c[d + 0];
    e[1] += r[d + 1] * c[d + 1];
    e[2] += r[d + 2] * c[d + 2];
    e[3] += r[d + 3] * c[d + 3];
  }
  return (e[0] + e[1]) + (e[2] + e[3]);
}
__device__ float np_dist(const float* __restrict__ resrow,
                         const float* __restrict__ crow, float r2) {
#pragma clang fp contract(off)
  float E = np_einsum256(resrow, crow);
  float c2 = np_sum256_sq(crow);
  float t1 = r2 - 2.0f * E;
  return t1 + c2;
}

// ---- prep: codebook -> fp16 B-fragment blobs; c2 ----
// Blob b = ((lvl*16+ch)*4 + t)*8 + s holds 64 lanes x 8 fp16 (16B/lane):
// lane (kq=lane>>4, n=lane&15): code = ch*64+t*16+n, k = s*32+kq*8+j.
__global__ void prep_blob(const float* __restrict__ cb,
                          unsigned short* __restrict__ wfp) {
  int U = blockIdx.x * 256 + threadIdx.x;   // 131072 16B-units
  int lane = U & 63, blob = U >> 6;
  int s = blob & 7, t = (blob >> 3) & 3, ch = (blob >> 5) & 15, lvl = blob >> 9;
  int code = ch * 64 + t * 16 + (lane & 15);
  int k0 = s * 32 + (lane >> 4) * 8;
  const float* p = cb + (size_t)(lvl * NK + code) * ND + k0;
  float4 x0 = *(const float4*)p;
  float4 x1 = *(const float4*)(p + 4);
  h8u u;
  u.h2[0] = __builtin_amdgcn_cvt_pkrtz(x0.x, x0.y);
  u.h2[1] = __builtin_amdgcn_cvt_pkrtz(x0.z, x0.w);
  u.h2[2] = __builtin_amdgcn_cvt_pkrtz(x1.x, x1.y);
  u.h2[3] = __builtin_amdgcn_cvt_pkrtz(x1.z, x1.w);
  ((uint4*)wfp)[U] = u.u;
}
__global__ void prep_c2(const float* __restrict__ cb, float* __restrict__ c2) {
  int k = blockIdx.x;
  int lane = threadIdx.x;
  const float* p = cb + (size_t)k * ND + lane * 4;
  double s = (double)p[0]*p[0] + (double)p[1]*p[1]
           + (double)p[2]*p[2] + (double)p[3]*p[3];
  for (int off = 32; off >= 1; off >>= 1) s += __shfl_down(s, off);
  if (lane == 0) c2[k] = (float)s;
}

// LDS map (39424 B):
//  bblob: half8[2048]   @0      (32768) one 64-code chunk, fragment order
//  c2s:   float[1024]   @32768  (4096)
//  selh:  int[128*4]    @36864  (2048)
//  flags: int[128]      @38912  (512)
// overlays (phase-disjoint, barrier-separated):
//  mscr:  float[128*16*4] @0      (32768)  top-2 merge dump
//  lred:  double[256]     @0      (2048)   loss reduction
//  resr:  float[256]      @32768  (1024)   rescan residual (over c2s)
//  redf:  float[256]      @33792  (1024)
//  redk:  int[256]        @34816  (1024)

__global__ __launch_bounds__(256, 4)
void rvq_main(const float* __restrict__ z, const float* __restrict__ cbf,
              const unsigned short* __restrict__ wfp,
              const float* __restrict__ c2w, float* __restrict__ out) {
  extern __shared__ char smem[];
  half8_t* bblob = (half8_t*)smem;
  float* c2s  = (float*)(smem + 32768);
  int*   selh = (int*)(smem + 36864);
  int*   flags= (int*)(smem + 38912);
  float* mscr = (float*)smem;
  double* lred= (double*)smem;
  float* resr = (float*)(smem + 32768);
  float* redf = (float*)(smem + 33792);
  int*   redk = (int*)(smem + 34816);

  const int tid  = threadIdx.x;
  const int wave = tid >> 6, lane = tid & 63;
  const int quad = lane >> 4, lx = lane & 15;
  const int blk  = blockIdx.x;

  for (int lvl = 0; lvl < NL; ++lvl) {
    __syncthreads();   // prev-level rescan reads done; c2s/selh stable
    // stage c2 for this level
#pragma unroll
    for (int t = 0; t < 4; ++t)
      c2s[t * 256 + tid] = c2w[lvl * NK + t * 256 + tid];

    // ---- build fp16 A-fragments (32 rows/wave, 64 VGPRs) ----
    half8_t A[2][8];
#pragma unroll
    for (int s = 0; s < 2; ++s) {
      const int rloc = wave * 32 + s * 16 + lx;
      const size_t rg = (size_t)(blk * MROWS + rloc);
      const float* cbase[NL];
      for (int l = 0; l < lvl; ++l)
        cbase[l] = cbf + (size_t)(l * NK + selh[rloc * 4 + l]) * ND;
#pragma unroll
      for (int ks = 0; ks < 8; ++ks) {
        const int k0 = ks * 32 + quad * 8;
        float4 p0 = *(const float4*)(z + rg * ND + k0);
        float4 p1 = *(const float4*)(z + rg * ND + k0 + 4);
        for (int l = 0; l < lvl; ++l) {
          float4 q0 = *(const float4*)(cbase[l] + k0);
          float4 q1 = *(const float4*)(cbase[l] + k0 + 4);
          p0.x -= q0.x; p0.y -= q0.y; p0.z -= q0.z; p0.w -= q0.w;
          p1.x -= q1.x; p1.y -= q1.y; p1.z -= q1.z; p1.w -= q1.w;
        }
        h8u u;
        u.h2[0] = __builtin_amdgcn_cvt_pkrtz(p0.x, p0.y);
        u.h2[1] = __builtin_amdgcn_cvt_pkrtz(p0.z, p0.w);
        u.h2[2] = __builtin_amdgcn_cvt_pkrtz(p1.x, p1.y);
        u.h2[3] = __builtin_amdgcn_cvt_pkrtz(p1.z, p1.w);
        A[s][ks] = u.v;
      }
    }

    // ---- screen: per-lane top-2 over 8 (stripe,reg) streams ----
    float m1[8], m2[8]; int i1[8];
#pragma unroll
    for (int t = 0; t < 8; ++t) { m1[t] = 1e30f; m2[t] = 1e30f; i1[t] = 0; }

#pragma unroll 1
    for (int ch = 0; ch < NCH; ++ch) {
      __syncthreads();   // bblob free (prev chunk consumed); orders c2s on ch=0
      {
        const uint4* src = (const uint4*)wfp + (size_t)(lvl * 16 + ch) * 2048;
        uint4* dst = (uint4*)smem;
#pragma unroll
        for (int i = 0; i < 8; ++i)
          dst[i * 256 + tid] = src[i * 256 + tid];   // lane-contiguous, conflict-free
      }
      __syncthreads();

#pragma unroll 1
      for (int t4 = 0; t4 < 4; ++t4) {
        f32x4 a0 = {0.f, 0.f, 0.f, 0.f}, a1 = {0.f, 0.f, 0.f, 0.f};
        const half8_t* bb = bblob + t4 * 512 + lane;   // 512 = 8 slices * 64 lanes
#pragma unroll
        for (int s = 0; s < 8; ++s) {
          half8_t bv = bb[s * 64];                     // ds_read_b128, conflict-free
          a0 = __builtin_amdgcn_mfma_f32_16x16x32_f16(A[0][s], bv, a0, 0, 0, 0);
          a1 = __builtin_amdgcn_mfma_f32_16x16x32_f16(A[1][s], bv, a1, 0, 0, 0);
        }
        const int kidx = ch * 64 + t4 * 16 + lx;
        const float c2v = c2s[kidx];
#pragma unroll
        for (int st = 0; st < 8; ++st) {
          float e = (st < 4) ? a0[st & 3] : a1[st & 3];
          float d = fmaf(-2.0f, e, c2v);
          if (d < m1[st]) { m2[st] = m1[st]; m1[st] = d; i1[st] = kidx; }
          else if (d < m2[st]) m2[st] = d;
        }
      }
    }

    // ---- cross-lane top-2 merge (mscr overlays bblob) ----
    __syncthreads();
#pragma unroll
    for (int t = 0; t < 8; ++t) {
      int rloc = wave * 32 + (t >> 2) * 16 + quad * 4 + (t & 3);
      float* p = mscr + (rloc * 16 + lx) * 4;
      p[0] = m1[t]; p[1] = m2[t]; p[2] = __int_as_float(i1[t]);
    }
    __syncthreads();
    if (tid < MROWS) {
      float gm1 = 1e30f, gm2 = 1e30f; int gi1 = 0x7fffffff;
      for (int t = 0; t < 16; ++t) {
        const float* p = mscr + (tid * 16 + t) * 4;
        float a1v = p[0], a2v = p[1]; int ai = __float_as_int(p[2]);
        if (a1v < gm1 || (a1v == gm1 && ai < gi1)) {
          gm2 = fminf(gm1, a2v); gm1 = a1v; gi1 = ai;
        } else {
          gm2 = fminf(gm2, a1v);
        }
      }
      selh[tid * 4 + lvl] = gi1;
      flags[tid] = (gm2 - gm1 <= FLAG_MARGIN) ? 1 : 0;
    }
    __syncthreads();

    // ---- numpy-bit-exact full-K rescan of flagged rows (~1.5%) ----
    for (int r = 0; r < MROWS; ++r) {
      if (flags[r]) {
        {
          float v = z[(size_t)(blk * MROWS + r) * ND + tid];
          for (int l = 0; l < lvl; ++l)
            v -= cbf[(size_t)(l * NK + selh[r * 4 + l]) * ND + tid];
          resr[tid] = v;
        }
        __syncthreads();
        float r2 = np_sum256_sq(resr);
        float bd = 1e30f; int bk = 0x7fffffff;
        for (int u = 0; u < 4; ++u) {
          int k = u * 256 + tid;
          float dd = np_dist(resr, cbf + (size_t)(lvl * NK + k) * ND, r2);
          if (dd < bd || (dd == bd && k < bk)) { bd = dd; bk = k; }
        }
        redf[tid] = bd; redk[tid] = bk;
        __syncthreads();
        if (tid == 0) {
          float gb = 1e30f; int gk = 0x7fffffff;
          for (int t2 = 0; t2 < 256; ++t2) {
            if (redf[t2] < gb || (redf[t2] == gb && redk[t2] < gk)) {
              gb = redf[t2]; gk = redk[t2];
            }
          }
          selh[r * 4 + lvl] = gk;
        }
        __syncthreads();
      }
    }
  }

  // ---- epilogue: z_q = sum of selected codes, codes, loss ----
  __syncthreads();
  double lacc = 0.0;
#pragma unroll 1
  for (int it = 0; it < 32; ++it) {
    int i = it * 256 + tid;
    int row = i >> 6, dc = i & 63;
    size_t rg = (size_t)(blk * MROWS + row);
    float4 z4 = *(const float4*)(z + rg * ND + dc * 4);
    float4 q; q.x = 0.f; q.y = 0.f; q.z = 0.f; q.w = 0.f;
    for (int l = 0; l < NL; ++l) {
      int sel = selh[row * 4 + l];
      float4 c4 = *(const float4*)(cbf + (size_t)(l * NK + sel) * ND + dc * 4);
      q.x += c4.x; q.y += c4.y; q.z += c4.z; q.w += c4.w;
    }
    *(float4*)(out + rg * ND + dc * 4) = q;
    float dx = q.x - z4.x, dy = q.y - z4.y, dz = q.z - z4.z, dw = q.w - z4.w;
    lacc += (double)dx * dx + (double)dy * dy + (double)dz * dz + (double)dw * dw;
  }
  if (tid < MROWS) {
    for (int l = 0; l < NL; ++l)
      out[(size_t)NB * ND + (size_t)(blk * MROWS + tid) * NL + l] =
          (float)selh[tid * 4 + l];
  }
  __syncthreads();
  lred[tid] = lacc;
  __syncthreads();
  if (tid == 0) {
    double s = 0.0;
    for (int t = 0; t < 256; ++t) s += lred[t];
    atomicAdd(out + (size_t)NB * ND + (size_t)NB * NL,
              (float)(s / ((double)NB * (double)ND)));
  }
}

extern "C" void kernel_launch(void* const* d_in, const int* in_sizes, int n_in,
                              void* d_out, int out_size, void* d_ws, size_t ws_size,
                              hipStream_t stream) {
  const float* z  = (const float*)d_in[0];
  const float* cb = (const float*)d_in[1];
  float* out = (float*)d_out;

  unsigned short* wfp = (unsigned short*)d_ws;           // 2 MB fp16 blobs
  float* c2w = (float*)(wfp + (size_t)NL * NK * ND);     // 16 KB

  // zero the loss slot (harness poisons d_out with 0xAA)
  (void)hipMemsetAsync((void*)(out + (size_t)NB * ND + (size_t)NB * NL), 0,
                       sizeof(float), stream);

  prep_blob<<<dim3(512), dim3(256), 0, stream>>>(cb, wfp);
  prep_c2<<<dim3(NL * NK), dim3(64), 0, stream>>>(cb, c2w);

  const size_t shmem = 39424;
  rvq_main<<<dim3(NBLK), dim3(256), shmem, stream>>>(z, cb, wfp, c2w, out);
}